// Round 8
// baseline (367.419 us; speedup 1.0000x reference)
//
#include <hip/hip_runtime.h>
#include <math.h>

#define B 16
#define CIN 512
#define COUT 512
#define SDIM 512
#define H 64
#define W 64

typedef short s16x8 __attribute__((ext_vector_type(8)));
typedef float f32x4 __attribute__((ext_vector_type(4)));
typedef float f32x16 __attribute__((ext_vector_type(16)));

__device__ __constant__ float LIN_SCALE  = 0.04419417382415922f;   // 1/sqrt(512)
__device__ __constant__ float CONV_SCALE = 0.014731391274719742f;  // 1/sqrt(512*9)

__device__ __forceinline__ ushort f2bf(float f) {
  unsigned u = __float_as_uint(f);
  return (ushort)((u + 0x7FFFu + ((u >> 16) & 1u)) >> 16);  // RNE
}

// pair-interleaved slot swizzle for xs (unchanged from R7):
// byte-in-row = (col>>1)*128 + slot_swz(col, octet)*16
__device__ __forceinline__ int slot_swz(int col, int o) {
  return ((col & 1) * 4 + o) ^ ((col >> 1) & 7);
}

#define GLOAD16(g, l)                                           \
  __builtin_amdgcn_global_load_lds(                             \
      (const __attribute__((address_space(1))) unsigned*)(g),   \
      (__attribute__((address_space(3))) unsigned*)(l), 16, 0, 0)

// ---------------------------------------------------------------------------
// Kernel 1: s[b,ci] = style[b,:] . style_w[ci,:] * lin_scale + style_b[ci]
// ---------------------------------------------------------------------------
__global__ __launch_bounds__(512) void style_mod_kernel(
    const float* __restrict__ style, const float* __restrict__ style_w,
    const float* __restrict__ style_b, float* __restrict__ s,
    float* __restrict__ s2) {
  const int b = blockIdx.x;
  const int ci = threadIdx.x;
  __shared__ float st[SDIM];
  st[ci] = style[b * SDIM + ci];
  __syncthreads();

  const float4* wr = reinterpret_cast<const float4*>(style_w + (size_t)ci * SDIM);
  float acc = 0.f;
#pragma unroll 4
  for (int k = 0; k < SDIM / 4; ++k) {
    float4 wv = wr[k];
    acc += st[4 * k + 0] * wv.x + st[4 * k + 1] * wv.y +
           st[4 * k + 2] * wv.z + st[4 * k + 3] * wv.w;
  }
  float v = acc * LIN_SCALE + style_b[ci];
  s[b * CIN + ci] = v;
  s2[b * CIN + ci] = v * v;
}

// ---------------------------------------------------------------------------
// Kernel 3: outscale[b,co] = conv_scale * rsqrt(conv_scale^2 * sum + 1e-8)
// ---------------------------------------------------------------------------
__global__ __launch_bounds__(512) void dcoef_kernel(
    const float* __restrict__ s2, const float* __restrict__ wsq,
    float* __restrict__ outscale) {
  const int b = blockIdx.x;
  const int co = threadIdx.x;
  __shared__ float sh[CIN];
  sh[co] = s2[b * CIN + co];
  __syncthreads();

  const float4* wr = reinterpret_cast<const float4*>(wsq + (size_t)co * CIN);
  float acc = 0.f;
#pragma unroll 4
  for (int k = 0; k < CIN / 4; ++k) {
    float4 wv = wr[k];
    acc += sh[4 * k + 0] * wv.x + sh[4 * k + 1] * wv.y +
           sh[4 * k + 2] * wv.z + sh[4 * k + 3] * wv.w;
  }
  float d = rsqrtf(acc * CONV_SCALE * CONV_SCALE + 1e-8f);
  outscale[b * COUT + co] = d * CONV_SCALE;
}

// ---------------------------------------------------------------------------
// Kernel P1 (fused wsq): pack weights -> direct-frag layout for global->VGPR
// A-loads:  wt2 frag index = ((chunk*9 + j)*16 + cog)*2 + ks   (frag = 1KB)
//           in-frag ushort off = (hi*32 + (co&31))*8, hi = octet&1
// Lane l of a frag load reads (co = l&31, octet = ks*2 + (l>>5)) -> the wave
// reads one contiguous 1KB run (perfectly coalesced). Also wsq[co][ci].
// ---------------------------------------------------------------------------
__global__ __launch_bounds__(256) void pack_w_kernel(
    const float* __restrict__ w, ushort* __restrict__ wt,
    float* __restrict__ wsq) {
  const int t = blockIdx.x * 256 + threadIdx.x;  // 32768 threads
  const int s = t & 3;                           // ci octet (0..3)
  const int chunk = (t >> 2) & 15;
  const int co = t >> 6;                         // global co
  const float4* wp =
      (const float4*)(w + ((size_t)co * 512 + chunk * 32 + s * 8) * 9);
  float wv[72];
#pragma unroll
  for (int i = 0; i < 18; ++i) {
    float4 v = wp[i];
    wv[4 * i + 0] = v.x; wv[4 * i + 1] = v.y;
    wv[4 * i + 2] = v.z; wv[4 * i + 3] = v.w;
  }
  // wsq fused: per-ci sum over 9 taps
  {
    float q[8];
#pragma unroll
    for (int i = 0; i < 8; ++i) {
      float a = 0.f;
#pragma unroll
      for (int k = 0; k < 9; ++k) {
        float v = wv[i * 9 + k];
        a += v * v;
      }
      q[i] = a;
    }
    float4* qd = (float4*)(wsq + (size_t)co * 512 + chunk * 32 + s * 8);
    qd[0] = make_float4(q[0], q[1], q[2], q[3]);
    qd[1] = make_float4(q[4], q[5], q[6], q[7]);
  }
#pragma unroll
  for (int j = 0; j < 9; ++j) {
    s16x8 p;
#pragma unroll
    for (int i = 0; i < 8; ++i) p[i] = (short)f2bf(wv[i * 9 + j]);
    size_t frag = ((size_t)(chunk * 9 + j) * 16 + (co >> 5)) * 2 + (s >> 1);
    size_t off = frag * 512 + (size_t)((s & 1) * 32 + (co & 31)) * 8;
    *(s16x8*)(wt + off) = p;
  }
}

// ---------------------------------------------------------------------------
// Kernel P2: pack x -> xp[b][chunk][gr][...] bf16, s folded in (R7 layout).
// ---------------------------------------------------------------------------
__global__ __launch_bounds__(256) void pack_x_kernel(
    const float* __restrict__ x, const float* __restrict__ smod,
    ushort* __restrict__ xp) {
  __shared__ float xt[32][65];
  __shared__ float sm[32];
  const int tid = threadIdx.x;
  const int gr = blockIdx.x, chunk = blockIdx.y, b = blockIdx.z;
  if (tid < 32) sm[tid] = smod[b * 512 + chunk * 32 + tid];
  {
    const int ci = tid >> 3, cq = tid & 7;
    const float4* rp = (const float4*)(
        x + (((size_t)b * 512 + chunk * 32 + ci) * 64 + gr) * 64 + cq * 8);
    float4 a = rp[0], c2 = rp[1];
    float* row = &xt[ci][cq * 8];
    row[0] = a.x; row[1] = a.y; row[2] = a.z; row[3] = a.w;
    row[4] = c2.x; row[5] = c2.y; row[6] = c2.z; row[7] = c2.w;
  }
  __syncthreads();
  const int c = tid >> 2, o = tid & 3;  // gc = c, ci octet = o
  s16x8 p;
#pragma unroll
  for (int i = 0; i < 8; ++i)
    p[i] = (short)f2bf(xt[o * 8 + i][c] * sm[o * 8 + i]);
  const int cc = c + 1;
  const int off_us = (cc >> 1) * 64 + slot_swz(cc, o) * 8 - 32;  // -64B base
  *(s16x8*)(xp + ((size_t)(b * 16 + chunk) * 64 + gr) * 2048 + off_us) = p;
}

// ---------------------------------------------------------------------------
// Kernel 7: A-from-global 32x32x16 MFMA conv; LDS holds xs only.
// Grid dim3(cb=8, hb=8, b=16): linear id % 8 == cb -> each XCD touches only
// its 576KB wt2 slice (L2-resident). 256 thr / 4 waves; tile 64co x 8rows x
// 64px; wave wid owns rows h0+2wid(+1). Per chunk per wave:
//   A: 36 global_load_dwordx4 (L2), depth-2 tap prefetch (af[3])
//   B: 48 ds_read_b128 (rolling 3-row cache), 10 gload_lds staging
//   144 mfma_f32_32x32x16_bf16
// D: col(px)=lane&31, row(co)=(reg&3)+8*(reg>>2)+4*(lane>>5)  [m74/m101].
// Dynamic LDS 42240 B. 2 blocks/CU (unified VGPR+AGPR budget ~256/wave).
// ---------------------------------------------------------------------------
#define DLDS7 42240

// all LOADA args are unroll-constants -> af indices static (rule #20)
#define LOADA(CK, T, BUF) {                                          \
    const int j_ = ((T) % 3) * 3 + ((T) / 3);                        \
    const size_t f0_ = ((size_t)((CK) * 9 + j_) * 16 + cb * 2) * 2;  \
    af[BUF][0][0] = wfr[(f0_ + 0) * 64 + lane];                      \
    af[BUF][0][1] = wfr[(f0_ + 1) * 64 + lane];                      \
    af[BUF][1][0] = wfr[(f0_ + 2) * 64 + lane];                      \
    af[BUF][1][1] = wfr[(f0_ + 3) * 64 + lane]; }

__global__ __launch_bounds__(256, 2) void conv_mfma7_kernel(
    const ushort* __restrict__ wt, const ushort* __restrict__ xp,
    const float* __restrict__ outscale, float* __restrict__ out) {
  extern __shared__ char smem[];  // xs[10][4224]

  const int tid = threadIdx.x;
  const int cb = blockIdx.x;  // 0..7  (XCD-pinned: id%8 == cb)
  const int hb = blockIdx.y;  // 0..7
  const int b  = blockIdx.z;  // 0..15
  const int h0 = hb * 8, co0 = cb * 64;
  const int lane = tid & 63, wid = tid >> 6;  // 4 waves
  const int l31 = lane & 31, hi = lane >> 5;

  // zero xs once: halo pair-halves + OOB edge rows stay zero all chunks
  {
    s16x8* p = (s16x8*)smem;
    for (int e = tid; e < 2640; e += 256) p[e] = (s16x8)0;
  }

  f32x16 acc[2][2][2];
#pragma unroll
  for (int rr = 0; rr < 2; ++rr)
#pragma unroll
    for (int mt = 0; mt < 2; ++mt)
#pragma unroll
      for (int nt = 0; nt < 2; ++nt) acc[rr][mt][nt] = (f32x16)0.f;

  int boff[3][2][2];  // [kw][nt][ks] swizzled xs byte offsets
#pragma unroll
  for (int kw = 0; kw < 3; ++kw)
#pragma unroll
    for (int nt = 0; nt < 2; ++nt)
#pragma unroll
      for (int ks = 0; ks < 2; ++ks) {
        int cc = nt * 32 + l31 + kw;
        boff[kw][nt][ks] = (cc >> 1) * 128 + slot_swz(cc, ks * 2 + hi) * 16;
      }

  const char* xsrc0 = (const char*)xp + (size_t)b * 4194304 + tid * 16;
  char* xdst = smem + 64 + tid * 16;
  const char* xb = smem + 2 * wid * 4224;  // wave's top xs row
  const s16x8* wfr = (const s16x8*)wt;     // 16B units; frag = 64 units

  __syncthreads();  // zero visible

  s16x8 af[3][2][2];
  LOADA(0, 0, 0);
  LOADA(0, 1, 1);

  for (int chunk = 0; chunk < 16; ++chunk) {
    const char* xsrc = xsrc0 + (size_t)chunk * 262144;
#pragma unroll
    for (int t = 0; t < 10; ++t) {
      int gr = h0 - 1 + t;
      if ((unsigned)gr < 64u)
        GLOAD16(xsrc + (size_t)gr * 4096, xdst + t * 4224);
    }
    __syncthreads();  // xs staged (drains af prefetch too; values in VGPRs)

    s16x8 bf[4][2][2];
#pragma unroll
    for (int t = 0; t < 9; ++t) {
      const int kw = t / 3, kh = t % 3;
      if (kh == 0) {  // rows 0,1 for this kw
#pragma unroll
        for (int q = 0; q < 2; ++q)
#pragma unroll
          for (int nt = 0; nt < 2; ++nt)
#pragma unroll
            for (int ks = 0; ks < 2; ++ks)
              bf[q][nt][ks] =
                  *(const s16x8*)(xb + q * 4224 + boff[kw][nt][ks]);
      }
      if (kh < 2) {  // rolling prefetch of row kh+2 (live rows <= 3)
        const int q = kh + 2;
#pragma unroll
        for (int nt = 0; nt < 2; ++nt)
#pragma unroll
          for (int ks = 0; ks < 2; ++ks)
            bf[q][nt][ks] =
                *(const s16x8*)(xb + q * 4224 + boff[kw][nt][ks]);
      }
      // A-frag prefetch, distance 2 (crosses into next chunk at t=7,8)
      if (t < 7) {
        LOADA(chunk, t + 2, (t + 2) % 3);
      } else {
        LOADA((chunk + 1) & 15, t - 7, (t + 2) % 3);
      }
      const int cur = t % 3;
#pragma unroll
      for (int ks = 0; ks < 2; ++ks)
#pragma unroll
        for (int rr = 0; rr < 2; ++rr)
#pragma unroll
          for (int nt = 0; nt < 2; ++nt) {
            acc[rr][0][nt] = __builtin_amdgcn_mfma_f32_32x32x16_bf16(
                af[cur][0][ks], bf[rr + kh][nt][ks], acc[rr][0][nt], 0, 0, 0);
            acc[rr][1][nt] = __builtin_amdgcn_mfma_f32_32x32x16_bf16(
                af[cur][1][ks], bf[rr + kh][nt][ks], acc[rr][1][nt], 0, 0, 0);
          }
    }
    __syncthreads();  // protect xs before next chunk's staging
  }

  // epilogue: D col(px)=l31, row(co)=(reg&3)+8*(reg>>2)+4*hi
#pragma unroll
  for (int mt = 0; mt < 2; ++mt) {
#pragma unroll
    for (int reg = 0; reg < 16; ++reg) {
      const int row = (reg & 3) + 8 * (reg >> 2) + 4 * hi;
      const int co = co0 + mt * 32 + row;
      const float osc = outscale[b * COUT + co];
      float* obase = out + ((size_t)b * COUT + co) * H * W;
#pragma unroll
      for (int rr = 0; rr < 2; ++rr) {
        const int h = h0 + 2 * wid + rr;
#pragma unroll
        for (int nt = 0; nt < 2; ++nt)
          obase[h * W + nt * 32 + l31] = acc[rr][mt][nt][reg] * osc;
      }
    }
  }
}

// ---------------------------------------------------------------------------
// Fallback conv (R2, proven, packless): raw x/weight/s inputs, ~630 us.
// ---------------------------------------------------------------------------
__global__ __launch_bounds__(256, 2) void conv_mfma_kernel(
    const float* __restrict__ x, const float* __restrict__ weight,
    const float* __restrict__ s, const float* __restrict__ outscale,
    float* __restrict__ out) {
  __shared__ ushort xs[6][66][32];
  __shared__ ushort ws[9][64][32];

  const int tid = threadIdx.x;
  const int hb = blockIdx.x;
  const int cb = blockIdx.y;
  const int b  = blockIdx.z;
  const int h0 = hb * 4;
  const int co0 = cb * 64;
  const int lane = tid & 63;
  const int wid = tid >> 6;
  const int l15 = lane & 15;
  const int l4  = lane >> 4;

  f32x4 acc[4][4];
#pragma unroll
  for (int mt = 0; mt < 4; ++mt)
#pragma unroll
    for (int nt = 0; nt < 4; ++nt) acc[mt][nt] = (f32x4)0.f;

  const int wq = tid & 3;
  const int wco = tid >> 2;

  for (int c0 = 0; c0 < CIN; c0 += 32) {
    {
      const float4* wp = reinterpret_cast<const float4*>(
          weight + ((size_t)(co0 + wco) * CIN + c0 + wq * 8) * 9);
      float wv[72];
#pragma unroll
      for (int t = 0; t < 18; ++t) {
        float4 v = wp[t];
        wv[4 * t + 0] = v.x; wv[4 * t + 1] = v.y;
        wv[4 * t + 2] = v.z; wv[4 * t + 3] = v.w;
      }
      float sv[8];
#pragma unroll
      for (int i = 0; i < 8; ++i) sv[i] = s[b * CIN + c0 + wq * 8 + i];
#pragma unroll
      for (int j = 0; j < 9; ++j) {
        s16x8 p;
#pragma unroll
        for (int i = 0; i < 8; ++i)
          p[i] = (short)f2bf(wv[i * 9 + j] * sv[i]);
        *reinterpret_cast<s16x8*>(&ws[j][wco][wq * 8]) = p;
      }
    }
#pragma unroll
    for (int it = 0; it < 7; ++it) {
      int e = tid + it * 256;
      if (e < 6 * 66 * 4) {
        int q = e & 3;
        int t2 = e >> 2;
        int cc = t2 % 66;
        int r = t2 / 66;
        int gr = h0 - 1 + r;
        int gc = cc - 1;
        s16x8 p;
        if ((unsigned)gr < H && (unsigned)gc < W) {
          const float* xp2 =
              x + (((size_t)b * CIN + c0 + q * 8) * H + gr) * W + gc;
#pragma unroll
          for (int i = 0; i < 8; ++i) p[i] = (short)f2bf(xp2[(size_t)i * H * W]);
        } else {
#pragma unroll
          for (int i = 0; i < 8; ++i) p[i] = 0;
        }
        *reinterpret_cast<s16x8*>(&xs[r][cc][q * 8]) = p;
      }
    }
    __syncthreads();

#pragma unroll
    for (int kh = 0; kh < 3; ++kh) {
#pragma unroll
      for (int kw = 0; kw < 3; ++kw) {
        const int j = kh * 3 + kw;
        s16x8 af[4], bf[4];
#pragma unroll
        for (int mt = 0; mt < 4; ++mt)
          af[mt] = *reinterpret_cast<const s16x8*>(
              &ws[j][mt * 16 + l15][l4 * 8]);
#pragma unroll
        for (int nt = 0; nt < 4; ++nt)
          bf[nt] = *reinterpret_cast<const s16x8*>(
              &xs[wid + kh][nt * 16 + l15 + kw][l4 * 8]);
#pragma unroll
        for (int mt = 0; mt < 4; ++mt)
#pragma unroll
          for (int nt = 0; nt < 4; ++nt)
            acc[mt][nt] = __builtin_amdgcn_mfma_f32_16x16x32_bf16(
                af[mt], bf[nt], acc[mt][nt], 0, 0, 0);
      }
    }
    __syncthreads();
  }

  const int h = h0 + wid;
#pragma unroll
  for (int mt = 0; mt < 4; ++mt) {
#pragma unroll
    for (int r = 0; r < 4; ++r) {
      const int co = co0 + mt * 16 + l4 * 4 + r;
      const float osc = outscale[b * COUT + co];
      float* orow = out + (((size_t)b * COUT + co) * H + h) * W;
#pragma unroll
      for (int nt = 0; nt < 4; ++nt)
        orow[nt * 16 + l15] = acc[mt][nt][r] * osc;
    }
  }
}

// ---------------------------------------------------------------------------
extern "C" void kernel_launch(void* const* d_in, const int* in_sizes, int n_in,
                              void* d_out, int out_size, void* d_ws,
                              size_t ws_size, hipStream_t stream) {
  const float* x = (const float*)d_in[0];
  const float* style = (const float*)d_in[1];
  const float* weight = (const float*)d_in[2];
  const float* style_w = (const float*)d_in[3];
  const float* style_b = (const float*)d_in[4];
  float* out = (float*)d_out;

  // workspace layout (bytes):
  //   0        s        (32768)
  //   32768    s2       (32768)
  //   65536    wsq      (1048576)
  //   1114112  outscale (32768)
  //   1146880  wt       (4718592)   packed bf16 weights (direct-frag layout)
  //   5865472  xp       (67108864)  packed bf16 x (s folded, pair-interleaved)
  char* wsb = (char*)d_ws;
  float* s = (float*)(wsb + 0);
  float* s2 = (float*)(wsb + 32768);
  float* wsq = (float*)(wsb + 65536);
  float* outscale = (float*)(wsb + 1114112);
  ushort* wt = (ushort*)(wsb + 1146880);
  ushort* xp = (ushort*)(wsb + 5865472);
  const size_t NEED = 72974336;

  hipError_t attr_ok = hipFuncSetAttribute(
      reinterpret_cast<const void*>(conv_mfma7_kernel),
      hipFuncAttributeMaxDynamicSharedMemorySize, DLDS7);

  style_mod_kernel<<<B, 512, 0, stream>>>(style, style_w, style_b, s, s2);
  pack_w_kernel<<<128, 256, 0, stream>>>(weight, wt, wsq);
  dcoef_kernel<<<B, 512, 0, stream>>>(s2, wsq, outscale);

  if (attr_ok == hipSuccess && ws_size >= NEED) {
    pack_x_kernel<<<dim3(64, 16, 16), 256, 0, stream>>>(x, s, xp);
    // grid (cb, hb, b): linear id % 8 == cb -> wt2 slice pinned per XCD
    conv_mfma7_kernel<<<dim3(8, 8, 16), 256, DLDS7, stream>>>(wt, xp, outscale,
                                                              out);
  } else {
    conv_mfma_kernel<<<dim3(16, 8, 16), 256, 0, stream>>>(x, weight, s,
                                                          outscale, out);
  }
}

// Round 9
// 352.365 us; speedup vs baseline: 1.0427x; 1.0427x over previous
//
#include <hip/hip_runtime.h>
#include <math.h>

#define B 16
#define CIN 512
#define COUT 512
#define SDIM 512
#define H 64
#define W 64

typedef short s16x8 __attribute__((ext_vector_type(8)));
typedef float f32x4 __attribute__((ext_vector_type(4)));
typedef float f32x16 __attribute__((ext_vector_type(16)));

__device__ __constant__ float LIN_SCALE  = 0.04419417382415922f;   // 1/sqrt(512)
__device__ __constant__ float CONV_SCALE = 0.014731391274719742f;  // 1/sqrt(512*9)

__device__ __forceinline__ ushort f2bf(float f) {
  unsigned u = __float_as_uint(f);
  return (ushort)((u + 0x7FFFu + ((u >> 16) & 1u)) >> 16);  // RNE
}

#define GLOAD16(g, l)                                           \
  __builtin_amdgcn_global_load_lds(                             \
      (const __attribute__((address_space(1))) unsigned*)(g),   \
      (__attribute__((address_space(3))) unsigned*)(l), 16, 0, 0)

// ---------------------------------------------------------------------------
// Kernel prep1 (fused): blocks 0..127 pack weights (+wsq); blocks 128..143
// compute s[b,ci] (style modulation), 256 thr each (2 ci per thread).
//
// Weight pack layout (octet-major, dense frag reads):
//   wt[chunk][j][cb][octet][co64][8ci] bf16
//   ushort strides: chunk 147456, j 16384, cb 2048, octet 512, co64 8
// A 32x32 frag read (fixed j,cb,mt,ks) then touches two dense 512B runs.
// ---------------------------------------------------------------------------
__global__ __launch_bounds__(256) void prep1_kernel(
    const float* __restrict__ w, const float* __restrict__ style,
    const float* __restrict__ style_w, const float* __restrict__ style_b,
    ushort* __restrict__ wt, float* __restrict__ wsq, float* __restrict__ s,
    float* __restrict__ s2) {
  const int tid = threadIdx.x;
  if (blockIdx.x < 128) {
    // ---- pack_w part
    const int t = blockIdx.x * 256 + tid;  // 32768 units
    const int so = t & 3;                  // ci octet
    const int chunk = (t >> 2) & 15;
    const int co = t >> 6;                 // global co
    const float4* wp =
        (const float4*)(w + ((size_t)co * 512 + chunk * 32 + so * 8) * 9);
    float wv[72];
#pragma unroll
    for (int i = 0; i < 18; ++i) {
      float4 v = wp[i];
      wv[4 * i + 0] = v.x; wv[4 * i + 1] = v.y;
      wv[4 * i + 2] = v.z; wv[4 * i + 3] = v.w;
    }
    // fused wsq
    {
      float q[8];
#pragma unroll
      for (int i = 0; i < 8; ++i) {
        float a = 0.f;
#pragma unroll
        for (int k = 0; k < 9; ++k) {
          float v = wv[i * 9 + k];
          a += v * v;
        }
        q[i] = a;
      }
      float4* qd = (float4*)(wsq + (size_t)co * 512 + chunk * 32 + so * 8);
      qd[0] = make_float4(q[0], q[1], q[2], q[3]);
      qd[1] = make_float4(q[4], q[5], q[6], q[7]);
    }
    const int cb = co >> 6, co64 = co & 63;
    ushort* dst = wt + (size_t)chunk * 147456 + (size_t)cb * 2048 +
                  (size_t)so * 512 + (size_t)co64 * 8;
#pragma unroll
    for (int j = 0; j < 9; ++j) {
      s16x8 p;
#pragma unroll
      for (int i = 0; i < 8; ++i) p[i] = (short)f2bf(wv[i * 9 + j]);
      *(s16x8*)(dst + (size_t)j * 16384) = p;
    }
  } else {
    // ---- style part: batch bb, 2 ci per thread
    const int bb = blockIdx.x - 128;
    __shared__ float st[SDIM];
    st[tid] = style[bb * SDIM + tid];
    st[tid + 256] = style[bb * SDIM + tid + 256];
    __syncthreads();
#pragma unroll
    for (int half = 0; half < 2; ++half) {
      const int ci = tid + half * 256;
      const float4* wr =
          reinterpret_cast<const float4*>(style_w + (size_t)ci * SDIM);
      float acc = 0.f;
#pragma unroll 4
      for (int k = 0; k < SDIM / 4; ++k) {
        float4 wv = wr[k];
        acc += st[4 * k + 0] * wv.x + st[4 * k + 1] * wv.y +
               st[4 * k + 2] * wv.z + st[4 * k + 3] * wv.w;
      }
      float v = acc * LIN_SCALE + style_b[ci];
      s[bb * CIN + ci] = v;
      s2[bb * CIN + ci] = v * v;
    }
  }
}

// ---------------------------------------------------------------------------
// Kernel dcoef: outscale[b,co] = conv_scale * rsqrt(conv_scale^2*sum + 1e-8)
// ---------------------------------------------------------------------------
__global__ __launch_bounds__(512) void dcoef_kernel(
    const float* __restrict__ s2, const float* __restrict__ wsq,
    float* __restrict__ outscale) {
  const int b = blockIdx.x;
  const int co = threadIdx.x;
  __shared__ float sh[CIN];
  sh[co] = s2[b * CIN + co];
  __syncthreads();

  const float4* wr = reinterpret_cast<const float4*>(wsq + (size_t)co * CIN);
  float acc = 0.f;
#pragma unroll 4
  for (int k = 0; k < CIN / 4; ++k) {
    float4 wv = wr[k];
    acc += sh[4 * k + 0] * wv.x + sh[4 * k + 1] * wv.y +
           sh[4 * k + 2] * wv.z + sh[4 * k + 3] * wv.w;
  }
  float d = rsqrtf(acc * CONV_SCALE * CONV_SCALE + 1e-8f);
  outscale[b * COUT + co] = d * CONV_SCALE;
}

// ---------------------------------------------------------------------------
// Kernel P2: pack x (s folded) -> octet-major:
//   xp[b][chunk][gr][octet][col64][8ci] bf16  (per-row 4 dense 1KB planes;
//   LDS adds the halo: plane stride in LDS is 1056B incl cols 0/65 zeros)
//   ushort strides: (b,chunk) 2048*64, gr 2048, octet 512, col 8
// ---------------------------------------------------------------------------
__global__ __launch_bounds__(256) void pack_x_kernel(
    const float* __restrict__ x, const float* __restrict__ smod,
    ushort* __restrict__ xp) {
  __shared__ float xt[32][65];
  __shared__ float sm[32];
  const int tid = threadIdx.x;
  const int gr = blockIdx.x, chunk = blockIdx.y, b = blockIdx.z;
  if (tid < 32) sm[tid] = smod[b * 512 + chunk * 32 + tid];
  {
    const int ci = tid >> 3, cq = tid & 7;
    const float4* rp = (const float4*)(
        x + (((size_t)b * 512 + chunk * 32 + ci) * 64 + gr) * 64 + cq * 8);
    float4 a = rp[0], c2 = rp[1];
    float* row = &xt[ci][cq * 8];
    row[0] = a.x; row[1] = a.y; row[2] = a.z; row[3] = a.w;
    row[4] = c2.x; row[5] = c2.y; row[6] = c2.z; row[7] = c2.w;
  }
  __syncthreads();
  const int c = tid & 63, o = tid >> 6;  // col 0..63, ci-octet 0..3
  s16x8 p;
#pragma unroll
  for (int i = 0; i < 8; ++i)
    p[i] = (short)f2bf(xt[o * 8 + i][c] * sm[o * 8 + i]);
  *(s16x8*)(xp + ((size_t)(b * 16 + chunk) * 64 + gr) * 2048 + o * 512 +
            c * 8) = p;
}

// ---------------------------------------------------------------------------
// Kernel 8: 32x32x16 MFMA conv, octet-major (dense-granule) LDS layout.
// 256 thr / 4 waves; tile 64 co x 8 rows x 64 px; wave wid owns rows
// h0+2wid(+1). Per chunk (kw-outer, B cached across kh):
//   36 A-reads + 48 B-reads (all dense-granule) -> 144 mfma; T5 setprio.
// LDS: ws[9][4 octet][64 co][16B] @0 (36864B),
//      xs[10 row][4 octet][66 col][16B] @36864 (42240B; cols 0/65 = halo 0).
// A addr = j*4096 + (2ks+hi)*1024 + (mt*32+l31)*16
// B addr = row*4224 + (2ks+hi)*1056 + (nt*32+l31+kw)*16
// D: col(px)=lane&31, row(co)=(reg&3)+8*(reg>>2)+4*(lane>>5)  [m74/m101].
// ---------------------------------------------------------------------------
#define XSOFF8 36864
#define DLDS8 79104

__global__ __launch_bounds__(256, 2) void conv_mfma8_kernel(
    const ushort* __restrict__ wt, const ushort* __restrict__ xp,
    const float* __restrict__ outscale, float* __restrict__ out) {
  extern __shared__ char smem[];

  const int tid = threadIdx.x;
  const int hb = blockIdx.x;  // 0..7
  const int cb = blockIdx.y;  // 0..7
  const int b  = blockIdx.z;  // 0..15
  const int h0 = hb * 8, co0 = cb * 64;
  const int lane = tid & 63, wid = tid >> 6;  // 4 waves
  const int l31 = lane & 31, hi = lane >> 5;

  // zero xs once: halo cols (0,65 of each octet plane) + OOB rows stay zero
  {
    s16x8* p = (s16x8*)(smem + XSOFF8);
    for (int e = tid; e < 2640; e += 256) p[e] = (s16x8)0;
  }

  f32x16 acc[2][2][2];
#pragma unroll
  for (int rr = 0; rr < 2; ++rr)
#pragma unroll
    for (int mt = 0; mt < 2; ++mt)
#pragma unroll
      for (int nt = 0; nt < 2; ++nt) acc[rr][mt][nt] = (f32x16)0.f;

  // loop-invariant byte offsets (dense-granule layout, no swizzle needed)
  int aoff[2][2];  // [mt][ks]
#pragma unroll
  for (int mt = 0; mt < 2; ++mt)
#pragma unroll
    for (int ks = 0; ks < 2; ++ks)
      aoff[mt][ks] = (ks * 2 + hi) * 1024 + (mt * 32 + l31) * 16;
  int boff[3][2][2];  // [kw][nt][ks]
#pragma unroll
  for (int kw = 0; kw < 3; ++kw)
#pragma unroll
    for (int nt = 0; nt < 2; ++nt)
#pragma unroll
      for (int ks = 0; ks < 2; ++ks)
        boff[kw][nt][ks] =
            (ks * 2 + hi) * 1056 + (nt * 32 + l31 + kw) * 16;

  // staging pointers: wave w covers octet-plane w of each row/tap
  const char* wsrc0 = (const char*)wt + cb * 4096 + wid * 1024 + lane * 16;
  const char* xsrc0 =
      (const char*)xp + (size_t)b * 4194304 + wid * 1024 + lane * 16;
  char* wdst = smem + wid * 1024 + lane * 16;
  char* xdst = smem + XSOFF8 + wid * 1056 + 16 + lane * 16;
  const char* wb = smem;
  const char* xb = smem + XSOFF8 + 2 * wid * 4224;  // wave's top xs row

  __syncthreads();  // zero visible

  for (int chunk = 0; chunk < 16; ++chunk) {
    const char* wsrc = wsrc0 + (size_t)chunk * 294912;
    const char* xsrc = xsrc0 + (size_t)chunk * 262144;
#pragma unroll
    for (int t = 0; t < 9; ++t)
      GLOAD16(wsrc + t * 32768, wdst + t * 4096);
#pragma unroll
    for (int t = 0; t < 10; ++t) {
      int gr = h0 - 1 + t;
      if ((unsigned)gr < 64u)
        GLOAD16(xsrc + (size_t)gr * 4096, xdst + t * 4224);
    }
    __syncthreads();  // staged data visible

#pragma unroll
    for (int kw = 0; kw < 3; ++kw) {
      // cache B-frags for this kw: 4 rows x 2 nt x 2 ks
      s16x8 bf[4][2][2];
#pragma unroll
      for (int q = 0; q < 4; ++q)
#pragma unroll
        for (int nt = 0; nt < 2; ++nt)
#pragma unroll
          for (int ks = 0; ks < 2; ++ks)
            bf[q][nt][ks] =
                *(const s16x8*)(xb + q * 4224 + boff[kw][nt][ks]);
#pragma unroll
      for (int kh = 0; kh < 3; ++kh) {
        const char* wj = wb + (kh * 3 + kw) * 4096;
#pragma unroll
        for (int ks = 0; ks < 2; ++ks) {
          s16x8 af0 = *(const s16x8*)(wj + aoff[0][ks]);
          s16x8 af1 = *(const s16x8*)(wj + aoff[1][ks]);
          __builtin_amdgcn_s_setprio(1);
#pragma unroll
          for (int rr = 0; rr < 2; ++rr)
#pragma unroll
            for (int nt = 0; nt < 2; ++nt) {
              acc[rr][0][nt] = __builtin_amdgcn_mfma_f32_32x32x16_bf16(
                  af0, bf[rr + kh][nt][ks], acc[rr][0][nt], 0, 0, 0);
              acc[rr][1][nt] = __builtin_amdgcn_mfma_f32_32x32x16_bf16(
                  af1, bf[rr + kh][nt][ks], acc[rr][1][nt], 0, 0, 0);
            }
          __builtin_amdgcn_s_setprio(0);
        }
      }
    }
    __syncthreads();  // protect LDS before next chunk's staging
  }

  // epilogue: D col(px)=l31, row(co)=(reg&3)+8*(reg>>2)+4*hi
#pragma unroll
  for (int mt = 0; mt < 2; ++mt) {
#pragma unroll
    for (int reg = 0; reg < 16; ++reg) {
      const int row = (reg & 3) + 8 * (reg >> 2) + 4 * hi;
      const int co = co0 + mt * 32 + row;
      const float osc = outscale[b * COUT + co];
      float* obase = out + ((size_t)b * COUT + co) * H * W;
#pragma unroll
      for (int rr = 0; rr < 2; ++rr) {
        const int h = h0 + 2 * wid + rr;
#pragma unroll
        for (int nt = 0; nt < 2; ++nt)
          obase[h * W + nt * 32 + l31] = acc[rr][mt][nt][reg] * osc;
      }
    }
  }
}

// ---------------------------------------------------------------------------
// Fallback conv (R2, proven, packless): raw x/weight/s inputs, ~630 us.
// ---------------------------------------------------------------------------
__global__ __launch_bounds__(256, 2) void conv_mfma_kernel(
    const float* __restrict__ x, const float* __restrict__ weight,
    const float* __restrict__ s, const float* __restrict__ outscale,
    float* __restrict__ out) {
  __shared__ ushort xs[6][66][32];
  __shared__ ushort ws[9][64][32];

  const int tid = threadIdx.x;
  const int hb = blockIdx.x;
  const int cb = blockIdx.y;
  const int b  = blockIdx.z;
  const int h0 = hb * 4;
  const int co0 = cb * 64;
  const int lane = tid & 63;
  const int wid = tid >> 6;
  const int l15 = lane & 15;
  const int l4  = lane >> 4;

  f32x4 acc[4][4];
#pragma unroll
  for (int mt = 0; mt < 4; ++mt)
#pragma unroll
    for (int nt = 0; nt < 4; ++nt) acc[mt][nt] = (f32x4)0.f;

  const int wq = tid & 3;
  const int wco = tid >> 2;

  for (int c0 = 0; c0 < CIN; c0 += 32) {
    {
      const float4* wp = reinterpret_cast<const float4*>(
          weight + ((size_t)(co0 + wco) * CIN + c0 + wq * 8) * 9);
      float wv[72];
#pragma unroll
      for (int t = 0; t < 18; ++t) {
        float4 v = wp[t];
        wv[4 * t + 0] = v.x; wv[4 * t + 1] = v.y;
        wv[4 * t + 2] = v.z; wv[4 * t + 3] = v.w;
      }
      float sv[8];
#pragma unroll
      for (int i = 0; i < 8; ++i) sv[i] = s[b * CIN + c0 + wq * 8 + i];
#pragma unroll
      for (int j = 0; j < 9; ++j) {
        s16x8 p;
#pragma unroll
        for (int i = 0; i < 8; ++i)
          p[i] = (short)f2bf(wv[i * 9 + j] * sv[i]);
        *reinterpret_cast<s16x8*>(&ws[j][wco][wq * 8]) = p;
      }
    }
#pragma unroll
    for (int it = 0; it < 7; ++it) {
      int e = tid + it * 256;
      if (e < 6 * 66 * 4) {
        int q = e & 3;
        int t2 = e >> 2;
        int cc = t2 % 66;
        int r = t2 / 66;
        int gr = h0 - 1 + r;
        int gc = cc - 1;
        s16x8 p;
        if ((unsigned)gr < H && (unsigned)gc < W) {
          const float* xp2 =
              x + (((size_t)b * CIN + c0 + q * 8) * H + gr) * W + gc;
#pragma unroll
          for (int i = 0; i < 8; ++i) p[i] = (short)f2bf(xp2[(size_t)i * H * W]);
        } else {
#pragma unroll
          for (int i = 0; i < 8; ++i) p[i] = 0;
        }
        *reinterpret_cast<s16x8*>(&xs[r][cc][q * 8]) = p;
      }
    }
    __syncthreads();

#pragma unroll
    for (int kh = 0; kh < 3; ++kh) {
#pragma unroll
      for (int kw = 0; kw < 3; ++kw) {
        const int j = kh * 3 + kw;
        s16x8 af[4], bf[4];
#pragma unroll
        for (int mt = 0; mt < 4; ++mt)
          af[mt] = *reinterpret_cast<const s16x8*>(
              &ws[j][mt * 16 + l15][l4 * 8]);
#pragma unroll
        for (int nt = 0; nt < 4; ++nt)
          bf[nt] = *reinterpret_cast<const s16x8*>(
              &xs[wid + kh][nt * 16 + l15 + kw][l4 * 8]);
#pragma unroll
        for (int mt = 0; mt < 4; ++mt)
#pragma unroll
          for (int nt = 0; nt < 4; ++nt)
            acc[mt][nt] = __builtin_amdgcn_mfma_f32_16x16x32_bf16(
                af[mt], bf[nt], acc[mt][nt], 0, 0, 0);
      }
    }
    __syncthreads();
  }

  const int h = h0 + wid;
#pragma unroll
  for (int mt = 0; mt < 4; ++mt) {
#pragma unroll
    for (int r = 0; r < 4; ++r) {
      const int co = co0 + mt * 16 + l4 * 4 + r;
      const float osc = outscale[b * COUT + co];
      float* orow = out + (((size_t)b * COUT + co) * H + h) * W;
#pragma unroll
      for (int nt = 0; nt < 4; ++nt)
        orow[nt * 16 + l15] = acc[mt][nt][r] * osc;
    }
  }
}

// ---------------------------------------------------------------------------
extern "C" void kernel_launch(void* const* d_in, const int* in_sizes, int n_in,
                              void* d_out, int out_size, void* d_ws,
                              size_t ws_size, hipStream_t stream) {
  const float* x = (const float*)d_in[0];
  const float* style = (const float*)d_in[1];
  const float* weight = (const float*)d_in[2];
  const float* style_w = (const float*)d_in[3];
  const float* style_b = (const float*)d_in[4];
  float* out = (float*)d_out;

  // workspace layout (bytes):
  //   0        s        (32768)
  //   32768    s2       (32768)
  //   65536    wsq      (1048576)
  //   1114112  outscale (32768)
  //   1146880  wt       (4718592)   packed bf16 weights (octet-major)
  //   5865472  xp       (67108864)  packed bf16 x (s folded, octet-major)
  char* wsb = (char*)d_ws;
  float* s = (float*)(wsb + 0);
  float* s2 = (float*)(wsb + 32768);
  float* wsq = (float*)(wsb + 65536);
  float* outscale = (float*)(wsb + 1114112);
  ushort* wt = (ushort*)(wsb + 1146880);
  ushort* xp = (ushort*)(wsb + 5865472);
  const size_t NEED = 72974336;

  hipError_t attr_ok = hipFuncSetAttribute(
      reinterpret_cast<const void*>(conv_mfma8_kernel),
      hipFuncAttributeMaxDynamicSharedMemorySize, DLDS8);

  if (attr_ok == hipSuccess && ws_size >= NEED) {
    prep1_kernel<<<144, 256, 0, stream>>>(weight, style, style_w, style_b, wt,
                                          wsq, s, s2);
    dcoef_kernel<<<B, 512, 0, stream>>>(s2, wsq, outscale);
    pack_x_kernel<<<dim3(64, 16, 16), 256, 0, stream>>>(x, s, xp);
    conv_mfma8_kernel<<<dim3(8, 8, 16), 256, DLDS8, stream>>>(wt, xp, outscale,
                                                              out);
  } else {
    prep1_kernel<<<144, 256, 0, stream>>>(weight, style, style_w, style_b, wt,
                                          wsq, s, s2);
    dcoef_kernel<<<B, 512, 0, stream>>>(s2, wsq, outscale);
    conv_mfma_kernel<<<dim3(16, 8, 16), 256, 0, stream>>>(x, weight, s,
                                                          outscale, out);
  }
}

// Round 10
// 334.401 us; speedup vs baseline: 1.0987x; 1.0537x over previous
//
#include <hip/hip_runtime.h>
#include <math.h>

#define B 16
#define CIN 512
#define COUT 512
#define SDIM 512
#define H 64
#define W 64

typedef short s16x8 __attribute__((ext_vector_type(8)));
typedef float f32x4 __attribute__((ext_vector_type(4)));
typedef float f32x16 __attribute__((ext_vector_type(16)));

__device__ __constant__ float LIN_SCALE  = 0.04419417382415922f;   // 1/sqrt(512)
__device__ __constant__ float CONV_SCALE = 0.014731391274719742f;  // 1/sqrt(512*9)

__device__ __forceinline__ ushort f2bf(float f) {
  unsigned u = __float_as_uint(f);
  return (ushort)((u + 0x7FFFu + ((u >> 16) & 1u)) >> 16);  // RNE
}

#define GLOAD16(g, l)                                           \
  __builtin_amdgcn_global_load_lds(                             \
      (const __attribute__((address_space(1))) unsigned*)(g),   \
      (__attribute__((address_space(3))) unsigned*)(l), 16, 0, 0)

// ---------------------------------------------------------------------------
// prep1 (fused): blocks 0..127 pack weights (+wsq); blocks 128..143 style-mod.
//
// wt layout (CB=16 chunks, octet-major, contiguous per (chunk,cb) slab):
//   wt[chunk32][cb8][j9][oct2][co64][8ci] bf16
//   ushort strides: chunk 73728, cb 9216, j 1024, oct 512, co 8
//   -> per-chunk ws slab for one cb = 18432 B contiguous.
// ---------------------------------------------------------------------------
__global__ __launch_bounds__(256) void prep1_kernel(
    const float* __restrict__ w, const float* __restrict__ style,
    const float* __restrict__ style_w, const float* __restrict__ style_b,
    ushort* __restrict__ wt, float* __restrict__ wsq, float* __restrict__ s,
    float* __restrict__ s2) {
  const int tid = threadIdx.x;
  if (blockIdx.x < 128) {
    const int t = blockIdx.x * 256 + tid;  // 32768 units
    const int so = t & 1;                  // ci octet within chunk
    const int chunk = (t >> 1) & 31;       // 32 chunks of 16 ci
    const int co = t >> 6;                 // global co
    const float4* wp = (const float4*)(
        w + ((size_t)co * 512 + chunk * 16 + so * 8) * 9);
    float wv[72];
#pragma unroll
    for (int i = 0; i < 18; ++i) {
      float4 v = wp[i];
      wv[4 * i + 0] = v.x; wv[4 * i + 1] = v.y;
      wv[4 * i + 2] = v.z; wv[4 * i + 3] = v.w;
    }
    // fused wsq
    {
      float q[8];
#pragma unroll
      for (int i = 0; i < 8; ++i) {
        float a = 0.f;
#pragma unroll
        for (int k = 0; k < 9; ++k) {
          float v = wv[i * 9 + k];
          a += v * v;
        }
        q[i] = a;
      }
      float4* qd = (float4*)(wsq + (size_t)co * 512 + chunk * 16 + so * 8);
      qd[0] = make_float4(q[0], q[1], q[2], q[3]);
      qd[1] = make_float4(q[4], q[5], q[6], q[7]);
    }
    const int cb = co >> 6, co64 = co & 63;
    ushort* dst = wt + (size_t)chunk * 73728 + (size_t)cb * 9216 +
                  (size_t)so * 512 + (size_t)co64 * 8;
#pragma unroll
    for (int j = 0; j < 9; ++j) {
      s16x8 p;
#pragma unroll
      for (int i = 0; i < 8; ++i) p[i] = (short)f2bf(wv[i * 9 + j]);
      *(s16x8*)(dst + (size_t)j * 1024) = p;
    }
  } else {
    const int bb = blockIdx.x - 128;
    __shared__ float st[SDIM];
    st[tid] = style[bb * SDIM + tid];
    st[tid + 256] = style[bb * SDIM + tid + 256];
    __syncthreads();
#pragma unroll
    for (int half = 0; half < 2; ++half) {
      const int ci = tid + half * 256;
      const float4* wr =
          reinterpret_cast<const float4*>(style_w + (size_t)ci * SDIM);
      float acc = 0.f;
#pragma unroll 4
      for (int k = 0; k < SDIM / 4; ++k) {
        float4 wv = wr[k];
        acc += st[4 * k + 0] * wv.x + st[4 * k + 1] * wv.y +
               st[4 * k + 2] * wv.z + st[4 * k + 3] * wv.w;
      }
      float v = acc * LIN_SCALE + style_b[ci];
      s[bb * CIN + ci] = v;
      s2[bb * CIN + ci] = v * v;
    }
  }
}

// ---------------------------------------------------------------------------
// dcoef: outscale[b,co] = conv_scale * rsqrt(conv_scale^2*sum + 1e-8)
// ---------------------------------------------------------------------------
__global__ __launch_bounds__(512) void dcoef_kernel(
    const float* __restrict__ s2, const float* __restrict__ wsq,
    float* __restrict__ outscale) {
  const int b = blockIdx.x;
  const int co = threadIdx.x;
  __shared__ float sh[CIN];
  sh[co] = s2[b * CIN + co];
  __syncthreads();

  const float4* wr = reinterpret_cast<const float4*>(wsq + (size_t)co * CIN);
  float acc = 0.f;
#pragma unroll 4
  for (int k = 0; k < CIN / 4; ++k) {
    float4 wv = wr[k];
    acc += sh[4 * k + 0] * wv.x + sh[4 * k + 1] * wv.y +
           sh[4 * k + 2] * wv.z + sh[4 * k + 3] * wv.w;
  }
  float d = rsqrtf(acc * CONV_SCALE * CONV_SCALE + 1e-8f);
  outscale[b * COUT + co] = d * CONV_SCALE;
}

// ---------------------------------------------------------------------------
// pack_x: x (s folded) -> xp[b][chunk32][oct2][gr64][col64][8ci] bf16
//   ushort strides: b 2097152, chunk 65536, oct 32768, gr 512, col 8
// Block handles a chunk-PAIR (32 ci) at one gr row, 256 thr.
// ---------------------------------------------------------------------------
__global__ __launch_bounds__(256) void pack_x_kernel(
    const float* __restrict__ x, const float* __restrict__ smod,
    ushort* __restrict__ xp) {
  __shared__ float xt[32][65];
  __shared__ float sm[32];
  const int tid = threadIdx.x;
  const int gr = blockIdx.x, cp = blockIdx.y, b = blockIdx.z;  // cp 0..15
  if (tid < 32) sm[tid] = smod[b * 512 + cp * 32 + tid];
  {
    const int ci = tid >> 3, cq = tid & 7;
    const float4* rp = (const float4*)(
        x + (((size_t)b * 512 + cp * 32 + ci) * 64 + gr) * 64 + cq * 8);
    float4 a = rp[0], c2 = rp[1];
    float* row = &xt[ci][cq * 8];
    row[0] = a.x; row[1] = a.y; row[2] = a.z; row[3] = a.w;
    row[4] = c2.x; row[5] = c2.y; row[6] = c2.z; row[7] = c2.w;
  }
  __syncthreads();
  const int c = tid & 63, o = tid >> 6;  // col, ci-octet-of-32 (0..3)
  s16x8 p;
#pragma unroll
  for (int i = 0; i < 8; ++i)
    p[i] = (short)f2bf(xt[o * 8 + i][c] * sm[o * 8 + i]);
  const int chunk = cp * 2 + (o >> 1), oct = o & 1;
  *(s16x8*)(xp + (size_t)b * 2097152 + (size_t)chunk * 65536 + oct * 32768 +
            gr * 512 + c * 8) = p;
}

// ---------------------------------------------------------------------------
// Kernel 9: dbuf-prefetch 32x32x16 MFMA conv, CB=16, 2 blocks/CU.
// 256 thr / 4 waves; tile 64 co x 8 rows x 64 px; wave wid owns rows
// h0+2wid(+1). 32 chunks; ONE __syncthreads per chunk:
//   sync (drains stage(c) -- issued a full compute phase ago => free)
//   stage(c+1, buf^1)   (fire-and-forget, flies across compute(c))
//   compute(c, buf): per chunk/wave 18 A-reads + 24 B-reads -> 72 mfma.
// LDS 79104 B: ws[2][9][oct2][co64][16B] @0 (2x18432),
//              xs[2][oct2][row10][1056B] @36864 (2x21120; col 0/65 halo = 0).
// A addr = j*2048 + hi*1024 + (mt*32+l31)*16       (dense 512B runs)
// B addr = hi*10560 + row*1056 + (nt*32+l31+kw)*16 (dense runs, 0 conflicts)
// D: col(px)=lane&31, row(co)=(reg&3)+8*(reg>>2)+4*(lane>>5)  [m74/m101].
// ---------------------------------------------------------------------------
#define CBUF_WS 18432
#define CBUF_XS 21120
#define XS_BASE 36864
#define DLDS9 79104

__global__ __launch_bounds__(256, 2) void conv_mfma9_kernel(
    const ushort* __restrict__ wt, const ushort* __restrict__ xp,
    const float* __restrict__ outscale, float* __restrict__ out) {
  extern __shared__ char smem[];

  const int tid = threadIdx.x;
  const int hb = blockIdx.x;  // 0..7
  const int cb = blockIdx.y;  // 0..7
  const int b  = blockIdx.z;  // 0..15
  const int h0 = hb * 8, co0 = cb * 64;
  const int lane = tid & 63, wid = tid >> 6;  // 4 waves
  const int l31 = lane & 31, hi = lane >> 5;

  // zero both xs buffers: halo cols + OOB edge rows stay zero all chunks
  {
    s16x8* p = (s16x8*)(smem + XS_BASE);
    for (int e = tid; e < 2640; e += 256) p[e] = (s16x8)0;
  }

  f32x16 acc[2][2][2];
#pragma unroll
  for (int rr = 0; rr < 2; ++rr)
#pragma unroll
    for (int mt = 0; mt < 2; ++mt)
#pragma unroll
      for (int nt = 0; nt < 2; ++nt) acc[rr][mt][nt] = (f32x16)0.f;

  // loop-invariant read offsets (dense-granule layout)
  int aoff[2];
#pragma unroll
  for (int mt = 0; mt < 2; ++mt)
    aoff[mt] = hi * 1024 + (mt * 32 + l31) * 16;
  int boff[3][2];
#pragma unroll
  for (int kw = 0; kw < 3; ++kw)
#pragma unroll
    for (int nt = 0; nt < 2; ++nt)
      boff[kw][nt] = hi * 10560 + (nt * 32 + l31 + kw) * 16;

  const char* wsrc0 = (const char*)wt + (size_t)cb * 18432;
  const char* xsrc0 = (const char*)xp + (size_t)b * 4194304;

  // stage one CB=16 chunk into buffer `buf`
  auto stage = [&](int chunk, int buf) {
    const char* wsrc = wsrc0 + (size_t)chunk * 147456;
    const char* xsrc = xsrc0 + (size_t)chunk * 131072;
    char* wd = smem + buf * CBUF_WS;
    char* xd = smem + XS_BASE + buf * CBUF_XS;
#pragma unroll
    for (int p = 0; p < 4; ++p)
      GLOAD16(wsrc + p * 4096 + tid * 16, wd + p * 4096 + tid * 16);
    if (tid < 128)  // remaining 2048 B of ws (waves 0,1)
      GLOAD16(wsrc + 16384 + tid * 16, wd + 16384 + tid * 16);
#pragma unroll
    for (int p = 0; p < 5; ++p) {
      int e = p * 4 + wid;  // 0..19 = (oct, row)
      int oct = (e >= 10) ? 1 : 0;
      int r = e - oct * 10;
      int gr = h0 - 1 + r;
      if ((unsigned)gr < 64u)
        GLOAD16(xsrc + oct * 65536 + gr * 1024 + lane * 16,
                xd + oct * 10560 + r * 1056 + 16 + lane * 16);
    }
  };

  auto compute = [&](int buf) {
    const char* wb2 = smem + buf * CBUF_WS;
    const char* xb2 = smem + XS_BASE + buf * CBUF_XS + 2 * wid * 1056;
#pragma unroll
    for (int kw = 0; kw < 3; ++kw) {
      s16x8 bf[4][2];  // rows 2wid..2wid+3, cached across kh
#pragma unroll
      for (int q = 0; q < 4; ++q)
#pragma unroll
        for (int nt = 0; nt < 2; ++nt)
          bf[q][nt] = *(const s16x8*)(xb2 + q * 1056 + boff[kw][nt]);
#pragma unroll
      for (int kh = 0; kh < 3; ++kh) {
        const char* wj = wb2 + (kh * 3 + kw) * 2048;
        s16x8 af0 = *(const s16x8*)(wj + aoff[0]);
        s16x8 af1 = *(const s16x8*)(wj + aoff[1]);
#pragma unroll
        for (int rr = 0; rr < 2; ++rr)
#pragma unroll
          for (int nt = 0; nt < 2; ++nt) {
            acc[rr][0][nt] = __builtin_amdgcn_mfma_f32_32x32x16_bf16(
                af0, bf[rr + kh][nt], acc[rr][0][nt], 0, 0, 0);
            acc[rr][1][nt] = __builtin_amdgcn_mfma_f32_32x32x16_bf16(
                af1, bf[rr + kh][nt], acc[rr][1][nt], 0, 0, 0);
          }
      }
    }
  };

  __syncthreads();  // zeros visible
  stage(0, 0);

  for (int c = 0; c < 32; ++c) {
    const int buf = c & 1;
    __syncthreads();  // drains stage(c): issued a full chunk ago -> ~free;
                      // also: all waves done reading buf^1 (chunk c-1)
    if (c + 1 < 32) stage(c + 1, buf ^ 1);
    compute(buf);
  }

  // epilogue: D col(px)=l31, row(co)=(reg&3)+8*(reg>>2)+4*hi
#pragma unroll
  for (int mt = 0; mt < 2; ++mt) {
#pragma unroll
    for (int reg = 0; reg < 16; ++reg) {
      const int row = (reg & 3) + 8 * (reg >> 2) + 4 * hi;
      const int co = co0 + mt * 32 + row;
      const float osc = outscale[b * COUT + co];
      float* obase = out + ((size_t)b * COUT + co) * H * W;
#pragma unroll
      for (int rr = 0; rr < 2; ++rr) {
        const int h = h0 + 2 * wid + rr;
#pragma unroll
        for (int nt = 0; nt < 2; ++nt)
          obase[h * W + nt * 32 + l31] = acc[rr][mt][nt][reg] * osc;
      }
    }
  }
}

// ---------------------------------------------------------------------------
// Fallback conv (R2, proven, packless): raw x/weight/s inputs, ~630 us.
// ---------------------------------------------------------------------------
__global__ __launch_bounds__(256, 2) void conv_mfma_kernel(
    const float* __restrict__ x, const float* __restrict__ weight,
    const float* __restrict__ s, const float* __restrict__ outscale,
    float* __restrict__ out) {
  __shared__ ushort xs[6][66][32];
  __shared__ ushort ws[9][64][32];

  const int tid = threadIdx.x;
  const int hb = blockIdx.x;
  const int cb = blockIdx.y;
  const int b  = blockIdx.z;
  const int h0 = hb * 4;
  const int co0 = cb * 64;
  const int lane = tid & 63;
  const int wid = tid >> 6;
  const int l15 = lane & 15;
  const int l4  = lane >> 4;

  f32x4 acc[4][4];
#pragma unroll
  for (int mt = 0; mt < 4; ++mt)
#pragma unroll
    for (int nt = 0; nt < 4; ++nt) acc[mt][nt] = (f32x4)0.f;

  const int wq = tid & 3;
  const int wco = tid >> 2;

  for (int c0 = 0; c0 < CIN; c0 += 32) {
    {
      const float4* wp = reinterpret_cast<const float4*>(
          weight + ((size_t)(co0 + wco) * CIN + c0 + wq * 8) * 9);
      float wv[72];
#pragma unroll
      for (int t = 0; t < 18; ++t) {
        float4 v = wp[t];
        wv[4 * t + 0] = v.x; wv[4 * t + 1] = v.y;
        wv[4 * t + 2] = v.z; wv[4 * t + 3] = v.w;
      }
      float sv[8];
#pragma unroll
      for (int i = 0; i < 8; ++i) sv[i] = s[b * CIN + c0 + wq * 8 + i];
#pragma unroll
      for (int j = 0; j < 9; ++j) {
        s16x8 p;
#pragma unroll
        for (int i = 0; i < 8; ++i)
          p[i] = (short)f2bf(wv[i * 9 + j] * sv[i]);
        *reinterpret_cast<s16x8*>(&ws[j][wco][wq * 8]) = p;
      }
    }
#pragma unroll
    for (int it = 0; it < 7; ++it) {
      int e = tid + it * 256;
      if (e < 6 * 66 * 4) {
        int q = e & 3;
        int t2 = e >> 2;
        int cc = t2 % 66;
        int r = t2 / 66;
        int gr = h0 - 1 + r;
        int gc = cc - 1;
        s16x8 p;
        if ((unsigned)gr < H && (unsigned)gc < W) {
          const float* xp2 =
              x + (((size_t)b * CIN + c0 + q * 8) * H + gr) * W + gc;
#pragma unroll
          for (int i = 0; i < 8; ++i) p[i] = (short)f2bf(xp2[(size_t)i * H * W]);
        } else {
#pragma unroll
          for (int i = 0; i < 8; ++i) p[i] = 0;
        }
        *reinterpret_cast<s16x8*>(&xs[r][cc][q * 8]) = p;
      }
    }
    __syncthreads();

#pragma unroll
    for (int kh = 0; kh < 3; ++kh) {
#pragma unroll
      for (int kw = 0; kw < 3; ++kw) {
        const int j = kh * 3 + kw;
        s16x8 af[4], bf[4];
#pragma unroll
        for (int mt = 0; mt < 4; ++mt)
          af[mt] = *reinterpret_cast<const s16x8*>(
              &ws[j][mt * 16 + l15][l4 * 8]);
#pragma unroll
        for (int nt = 0; nt < 4; ++nt)
          bf[nt] = *reinterpret_cast<const s16x8*>(
              &xs[wid + kh][nt * 16 + l15 + kw][l4 * 8]);
#pragma unroll
        for (int mt = 0; mt < 4; ++mt)
#pragma unroll
          for (int nt = 0; nt < 4; ++nt)
            acc[mt][nt] = __builtin_amdgcn_mfma_f32_16x16x32_bf16(
                af[mt], bf[nt], acc[mt][nt], 0, 0, 0);
      }
    }
    __syncthreads();
  }

  const int h = h0 + wid;
#pragma unroll
  for (int mt = 0; mt < 4; ++mt) {
#pragma unroll
    for (int r = 0; r < 4; ++r) {
      const int co = co0 + mt * 16 + l4 * 4 + r;
      const float osc = outscale[b * COUT + co];
      float* orow = out + (((size_t)b * COUT + co) * H + h) * W;
#pragma unroll
      for (int nt = 0; nt < 4; ++nt)
        orow[nt * 16 + l15] = acc[mt][nt][r] * osc;
    }
  }
}

// ---------------------------------------------------------------------------
extern "C" void kernel_launch(void* const* d_in, const int* in_sizes, int n_in,
                              void* d_out, int out_size, void* d_ws,
                              size_t ws_size, hipStream_t stream) {
  const float* x = (const float*)d_in[0];
  const float* style = (const float*)d_in[1];
  const float* weight = (const float*)d_in[2];
  const float* style_w = (const float*)d_in[3];
  const float* style_b = (const float*)d_in[4];
  float* out = (float*)d_out;

  // workspace layout (bytes):
  //   0        s        (32768)
  //   32768    s2       (32768)
  //   65536    wsq      (1048576)
  //   1114112  outscale (32768)
  //   1146880  wt       (4718592)   packed bf16 weights (CB16 octet-major)
  //   5865472  xp       (67108864)  packed bf16 x (s folded, CB16 octet-major)
  char* wsb = (char*)d_ws;
  float* s = (float*)(wsb + 0);
  float* s2 = (float*)(wsb + 32768);
  float* wsq = (float*)(wsb + 65536);
  float* outscale = (float*)(wsb + 1114112);
  ushort* wt = (ushort*)(wsb + 1146880);
  ushort* xp = (ushort*)(wsb + 5865472);
  const size_t NEED = 72974336;

  hipError_t attr_ok = hipFuncSetAttribute(
      reinterpret_cast<const void*>(conv_mfma9_kernel),
      hipFuncAttributeMaxDynamicSharedMemorySize, DLDS9);

  if (attr_ok == hipSuccess && ws_size >= NEED) {
    prep1_kernel<<<144, 256, 0, stream>>>(weight, style, style_w, style_b, wt,
                                          wsq, s, s2);
    dcoef_kernel<<<B, 512, 0, stream>>>(s2, wsq, outscale);
    pack_x_kernel<<<dim3(64, 16, 16), 256, 0, stream>>>(x, s, xp);
    conv_mfma9_kernel<<<dim3(8, 8, 16), 256, DLDS9, stream>>>(wt, xp, outscale,
                                                              out);
  } else {
    prep1_kernel<<<144, 256, 0, stream>>>(weight, style, style_w, style_b, wt,
                                          wsq, s, s2);
    dcoef_kernel<<<B, 512, 0, stream>>>(s2, wsq, outscale);
    conv_mfma_kernel<<<dim3(16, 8, 16), 256, 0, stream>>>(x, weight, s,
                                                          outscale, out);
  }
}